// Round 2
// baseline (3816.965 us; speedup 1.0000x reference)
//
#include <hip/hip_runtime.h>

typedef float f32x4 __attribute__((ext_vector_type(4)));
typedef _Float16 f16x8 __attribute__((ext_vector_type(8)));

#define B_TOT   1024
#define D_DIM   128
#define H_DIM   512
#define N_STEPS 500
#define ROWS    4     // batch rows per block
#define WAVES   4     // waves per block
#define HC      128   // H-chunk per wave

// f32 -> fp16 bits (RNE via v_cvt_f16_f32)
static __device__ __forceinline__ short f16b(float f) {
    _Float16 h = (_Float16)f;
    return __builtin_bit_cast(short, h);
}
static __device__ __forceinline__ float f16tof(short s) {
    return (float)__builtin_bit_cast(_Float16, s);
}

// tanh(x) = 1 - 2/(e^{2x}+1);  e^{2x} = exp2(2*log2(e)*x)
static __device__ __forceinline__ float tanh_fast(float x) {
    float e = __builtin_amdgcn_exp2f(x * 2.885390081777927f);
    return 1.0f - 2.0f * __builtin_amdgcn_rcpf(e + 1.0f);
}

__global__ __launch_bounds__(256, 1) void ndde_kernel(
    const float* __restrict__ x0, const float* __restrict__ tau,
    const float* __restrict__ W1, const float* __restrict__ b1,
    const float* __restrict__ W2, const float* __restrict__ b2,
    float* __restrict__ out)
{
    // padded rows (136 shorts = 272 B, 16B-aligned) to spread LDS banks
    __shared__ __align__(16) short x_hi[4][136];             // current x hi, fp16
    __shared__ __align__(16) short x_lo[4][136];             // current x residual, fp16
    __shared__ __align__(16) short hist_hi[11][4][136];      // delay buffer hi
    __shared__ __align__(16) short hist_lo[11][4][136];      // delay buffer lo
    __shared__ __align__(16) short bounce_hi[WAVES][4][136]; // h hi per wave
    __shared__ __align__(16) short bounce_lo[WAVES][4][136]; // h residual per wave
    __shared__ __align__(16) float slab[128][20];            // GEMM2 partials [d][4w+r]
    __shared__ __align__(16) float x_f32[128][4];            // current x, f32 [d][r]

    const int tid  = threadIdx.x;
    const int w    = tid >> 6;
    const int l    = tid & 63;
    const int l15  = l & 15;
    const int g    = l >> 4;
    const int rdup = l15 & 3;
    const int r0   = blockIdx.x * ROWS;

    const float dtv = tau[0] * 0.1f;

    // ---------------- weight fragments -> registers (fp16) ----------------
    const int hw0 = HC * w;
    f16x8 w1f[8][8];   // [n-tile over HC][k-step over 256]
    f16x8 w2f[8][4];   // [n-tile over D=128][k-step over HC]
    float b1f[8], w1tf[8];

#pragma unroll
    for (int nt = 0; nt < 8; ++nt) {
        const int hr = hw0 + 16 * nt + l15;           // W1 row (h index)
        const float* wr = W1 + (long)hr * 257;
#pragma unroll
        for (int ks = 0; ks < 8; ++ks) {
            const int c0 = 32 * ks + 8 * g;           // k = col (x: 0-127, y: 128-255)
            f16x8 f;
#pragma unroll
            for (int j = 0; j < 8; ++j) f[j] = (_Float16)wr[c0 + j];
            w1f[nt][ks] = f;
        }
        b1f[nt]  = b1[hr];
        w1tf[nt] = wr[256];                            // t column
    }
#pragma unroll
    for (int nt = 0; nt < 8; ++nt) {
        const int d = 16 * nt + l15;                   // W2 row (d index)
        const float* wr = W2 + (long)d * 512;
#pragma unroll
        for (int ks = 0; ks < 4; ++ks) {
            const int c0 = hw0 + 32 * ks + 8 * g;      // k = h index within chunk
            f16x8 f;
#pragma unroll
            for (int j = 0; j < 8; ++j) f[j] = (_Float16)wr[c0 + j];
            w2f[nt][ks] = f;
        }
    }

    // ---------------- state init ----------------
    float b2v = 0.0f;
    if (tid < 128) {
        b2v = b2[tid];
#pragma unroll
        for (int r = 0; r < ROWS; ++r) {
            float v = x0[(long)(r0 + r) * D_DIM + tid];
            x_f32[tid][r] = v;
            short hb = f16b(v);
            short lb = f16b(v - f16tof(hb));
            x_hi[r][tid] = hb;
            x_lo[r][tid] = lb;
            for (int s = 0; s < 11; ++s) { hist_hi[s][r][tid] = hb; hist_lo[s][r][tid] = lb; }
            out[(long)(r0 + r) * D_DIM + tid] = v;     // out[0] = x0
        }
    }
    __syncthreads();

    // ---------------- time-step loop ----------------
#pragma clang loop unroll(disable)
    for (int n = 0; n < N_STEPS; ++n) {
        const float t = (float)n * dtv;
        const int yslot = (n + 1) % 11;   // holds x_{n-10}; overwritten with x_{n+1} later

        // GEMM1: acc1 = [x ; y] @ W1_chunk^T  (+ b1 + t*w1t preloaded), split hi/lo
        f32x4 acc1[8];
#pragma unroll
        for (int nt = 0; nt < 8; ++nt) {
            float sb = fmaf(t, w1tf[nt], b1f[nt]);
            acc1[nt] = (f32x4){sb, sb, sb, sb};
        }
#pragma unroll
        for (int ks = 0; ks < 4; ++ks) {
            f16x8 xa = *(const f16x8*)&x_hi[rdup][32 * ks + 8 * g];
            f16x8 xl = *(const f16x8*)&x_lo[rdup][32 * ks + 8 * g];
#pragma unroll
            for (int nt = 0; nt < 8; ++nt)
                acc1[nt] = __builtin_amdgcn_mfma_f32_16x16x32_f16(xa, w1f[nt][ks], acc1[nt], 0, 0, 0);
#pragma unroll
            for (int nt = 0; nt < 8; ++nt)
                acc1[nt] = __builtin_amdgcn_mfma_f32_16x16x32_f16(xl, w1f[nt][ks], acc1[nt], 0, 0, 0);
        }
#pragma unroll
        for (int ks = 0; ks < 4; ++ks) {
            f16x8 ya = *(const f16x8*)&hist_hi[yslot][rdup][32 * ks + 8 * g];
            f16x8 yl = *(const f16x8*)&hist_lo[yslot][rdup][32 * ks + 8 * g];
#pragma unroll
            for (int nt = 0; nt < 8; ++nt)
                acc1[nt] = __builtin_amdgcn_mfma_f32_16x16x32_f16(ya, w1f[nt][ks + 4], acc1[nt], 0, 0, 0);
#pragma unroll
            for (int nt = 0; nt < 8; ++nt)
                acc1[nt] = __builtin_amdgcn_mfma_f32_16x16x32_f16(yl, w1f[nt][ks + 4], acc1[nt], 0, 0, 0);
        }

        // tanh + hi/lo split + relayout C->A through LDS.
        // C frag is batch-row-duplicated across lane groups: group g owns n-tiles 2g, 2g+1.
#pragma unroll
        for (int i = 0; i < 2; ++i) {
            const int nt = 2 * g + i;
#pragma unroll
            for (int r = 0; r < 4; ++r) {
                float h = tanh_fast(acc1[nt][r]);
                short hh = f16b(h);
                bounce_hi[w][r][16 * nt + l15] = hh;
                bounce_lo[w][r][16 * nt + l15] = f16b(h - f16tof(hh));
            }
        }

        // GEMM2 partial: acc2 = h_chunk @ W2_chunk^T, split hi/lo
        f32x4 acc2[8];
#pragma unroll
        for (int nt = 0; nt < 8; ++nt) acc2[nt] = (f32x4){0.f, 0.f, 0.f, 0.f};
#pragma unroll
        for (int ks = 0; ks < 4; ++ks) {
            f16x8 ha = *(const f16x8*)&bounce_hi[w][rdup][32 * ks + 8 * g];
            f16x8 hl = *(const f16x8*)&bounce_lo[w][rdup][32 * ks + 8 * g];
#pragma unroll
            for (int nt = 0; nt < 8; ++nt)
                acc2[nt] = __builtin_amdgcn_mfma_f32_16x16x32_f16(ha, w2f[nt][ks], acc2[nt], 0, 0, 0);
#pragma unroll
            for (int nt = 0; nt < 8; ++nt)
                acc2[nt] = __builtin_amdgcn_mfma_f32_16x16x32_f16(hl, w2f[nt][ks], acc2[nt], 0, 0, 0);
        }

        // write K-split partials to slabs (group g owns n-tiles 2g, 2g+1)
#pragma unroll
        for (int i = 0; i < 2; ++i) {
            const int nt = 2 * g + i;
            *(f32x4*)&slab[16 * nt + l15][4 * w] = acc2[nt];
        }
        __syncthreads();

        // reduce + Euler update + emit (threads 0..127, one per d)
        if (tid < 128) {
            f32x4 s = *(const f32x4*)&slab[tid][0];
#pragma unroll
            for (int wv = 1; wv < WAVES; ++wv)
                s += *(const f32x4*)&slab[tid][4 * wv];
            f32x4 xo = *(const f32x4*)&x_f32[tid][0];
            f32x4 xn;
#pragma unroll
            for (int r = 0; r < 4; ++r)
                xn[r] = xo[r] + dtv * (s[r] + b2v);
            *(f32x4*)&x_f32[tid][0] = xn;
            float* op = out + (long)(n + 1) * (B_TOT * D_DIM) + (long)r0 * D_DIM + tid;
#pragma unroll
            for (int r = 0; r < 4; ++r) {
                float v = xn[r];
                short hb = f16b(v);
                short lb = f16b(v - f16tof(hb));
                x_hi[r][tid] = hb;
                x_lo[r][tid] = lb;
                hist_hi[yslot][r][tid] = hb;     // x_{n+1} -> slot (n+1)%11
                hist_lo[yslot][r][tid] = lb;
                op[r * D_DIM] = v;
            }
        }
        __syncthreads();
    }
}

extern "C" void kernel_launch(void* const* d_in, const int* in_sizes, int n_in,
                              void* d_out, int out_size, void* d_ws, size_t ws_size,
                              hipStream_t stream) {
    (void)in_sizes; (void)n_in; (void)out_size; (void)d_ws; (void)ws_size;
    const float* x0  = (const float*)d_in[0];
    const float* tau = (const float*)d_in[1];
    const float* W1  = (const float*)d_in[2];
    const float* b1  = (const float*)d_in[3];
    const float* W2  = (const float*)d_in[4];
    const float* b2  = (const float*)d_in[5];
    float* out = (float*)d_out;

    ndde_kernel<<<dim3(B_TOT / ROWS), dim3(64 * WAVES), 0, stream>>>(
        x0, tau, W1, b1, W2, b2, out);
}

// Round 3
// 948.105 us; speedup vs baseline: 4.0259x; 4.0259x over previous
//
#include <hip/hip_runtime.h>

typedef float f32x4 __attribute__((ext_vector_type(4)));
typedef _Float16 f16x8 __attribute__((ext_vector_type(8)));

#define B_TOT   1024
#define D_DIM   128
#define H_DIM   512
#define N_STEPS 500
#define ROWS    4      // batch rows per block
#define WAVES   8      // waves per block

#define HSTRIDE 272                 // bytes per hist row (128 shorts + pad)
#define HSLOT   (8 * HSTRIDE)       // 8 rows (4 hi + 4 lo) per slot
#define BSTRIDE 1056                // bytes per bounce row (512 shorts + pad)
#define LDS_BOUNCE (11 * HSLOT)     // hist occupies [0, 11*HSLOT)
#define LDS_TOTAL  (LDS_BOUNCE + 8 * BSTRIDE)

static __device__ __forceinline__ short f16b(float f) {
    _Float16 h = (_Float16)f;
    return __builtin_bit_cast(short, h);
}
static __device__ __forceinline__ float f16tof(short s) {
    return (float)__builtin_bit_cast(_Float16, s);
}
static __device__ __forceinline__ float tanh_fast(float x) {
    float e = __builtin_amdgcn_exp2f(x * 2.885390081777927f);
    return 1.0f - 2.0f * __builtin_amdgcn_rcpf(e + 1.0f);
}
static __device__ __forceinline__ f32x4 sx32(f32x4 v) {
    f32x4 r;
#pragma unroll
    for (int i = 0; i < 4; ++i) r[i] = __shfl_xor(v[i], 32);
    return r;
}
// dynamic element pick via cndmask tree (no scratch)
static __device__ __forceinline__ float pick(f32x4 v, int g) {
    float lo = (g & 1) ? v[1] : v[0];
    float hi = (g & 1) ? v[3] : v[2];
    return (g & 2) ? hi : lo;
}

__global__ __launch_bounds__(512, 2) void ndde_kernel(
    const float* __restrict__ x0, const float* __restrict__ tau,
    const float* __restrict__ W1, const float* __restrict__ b1,
    const float* __restrict__ W2, const float* __restrict__ b2,
    float* __restrict__ out)
{
    __shared__ __align__(16) char smem[LDS_TOTAL];

    const int tid = threadIdx.x;
    const int w   = tid >> 6;
    const int l   = tid & 63;
    const int g   = l >> 4;
    const int l15 = l & 15;
    // A-frag row = l15; rows [0-3]=hi r0-3, [4-7]=dup, [8-11]=lo r0-3, [12-15]=dup
    const int ur  = (l15 & 3) | ((l15 >> 3) << 2);   // storage row 0..7
    const int r0  = blockIdx.x * ROWS;
    const int d   = 16 * w + l15;                    // this lane's owned d-col

    const float dtv = tau[0] * 0.1f;

    // ---------------- weights -> registers (fp16) ----------------
    f16x8 w1f[4][8];   // [nt over 64 h-rows][ks over K=256]
    f16x8 w2f[16];     // [ks over K=512], n-tile = d-cols [16w,16w+16)
    float b1f[4], w1tf[4];

#pragma unroll
    for (int nt = 0; nt < 4; ++nt) {
        const int hr = 64 * w + 16 * nt + l15;
        const float* wr = W1 + (long)hr * 257;
#pragma unroll
        for (int ks = 0; ks < 8; ++ks) {
            const int c0 = 32 * ks + 8 * g;
            f16x8 f;
#pragma unroll
            for (int j = 0; j < 8; ++j) f[j] = (_Float16)wr[c0 + j];
            w1f[nt][ks] = f;
        }
        b1f[nt]  = b1[hr];
        w1tf[nt] = wr[256];
    }
    {
        const float* wr = W2 + (long)d * 512;
#pragma unroll
        for (int ks = 0; ks < 16; ++ks) {
            const int c0 = 32 * ks + 8 * g;
            f16x8 f;
#pragma unroll
            for (int j = 0; j < 8; ++j) f[j] = (_Float16)wr[c0 + j];
            w2f[ks] = f;
        }
    }
    const float b2v = b2[d];
    float xo = x0[(long)(r0 + g) * D_DIM + d];   // lane-owned state (r=g, d)

    // ---------------- init hist ring + out[0] ----------------
    {
        short hb = f16b(xo);
        short lb = f16b(xo - f16tof(hb));
        for (int s = 0; s < 11; ++s) {
            *(short*)(smem + s * HSLOT + g * HSTRIDE + 2 * d)       = hb;
            *(short*)(smem + s * HSLOT + (g + 4) * HSTRIDE + 2 * d) = lb;
        }
        out[(long)(r0 + g) * D_DIM + d] = xo;
    }
    __syncthreads();

    // per-lane invariant LDS offsets
    const int histRd   = ur * HSTRIDE + 16 * g;                              // + slot*HSLOT + 64*ks
    const int bounceRd = LDS_BOUNCE + ur * BSTRIDE + ((16 * g) ^ ((ur & 3) << 4)); // + 64*ks
    const int bwXor    = g << 4;   // write-side XOR (row u: u&3 == g for both hi and lo)

    float* po = out + (long)(B_TOT * D_DIM) + (long)(r0 + g) * D_DIM + d;

    int cur = 0;   // hist slot holding x_n
    int ys  = 1;   // slot holding y = x_{n-10}; overwritten with x_{n+1}

#pragma clang loop unroll(disable)
    for (int n = 0; n < N_STEPS; ++n) {
        const float t = (float)n * dtv;

        // -------- GEMM1: hi/lo packed in M-rows --------
        f32x4 acc1[4];
#pragma unroll
        for (int nt = 0; nt < 4; ++nt) acc1[nt] = (f32x4){0.f, 0.f, 0.f, 0.f};

        const char* xb = smem + cur * HSLOT + histRd;
        const char* yb = smem + ys * HSLOT + histRd;
#pragma unroll
        for (int ks = 0; ks < 4; ++ks) {
            f16x8 xa = *(const f16x8*)(xb + 64 * ks);
#pragma unroll
            for (int nt = 0; nt < 4; ++nt)
                acc1[nt] = __builtin_amdgcn_mfma_f32_16x16x32_f16(xa, w1f[nt][ks], acc1[nt], 0, 0, 0);
        }
#pragma unroll
        for (int ks = 0; ks < 4; ++ks) {
            f16x8 ya = *(const f16x8*)(yb + 64 * ks);
#pragma unroll
            for (int nt = 0; nt < 4; ++nt)
                acc1[nt] = __builtin_amdgcn_mfma_f32_16x16x32_f16(ya, w1f[nt][ks + 4], acc1[nt], 0, 0, 0);
        }

        // combine hi+lo rows (lane^32), tanh (g-split: lane handles batch r=g), write bounce
#pragma unroll
        for (int nt = 0; nt < 4; ++nt) {
            f32x4 c = acc1[nt];
            c += sx32(c);
            float hp = pick(c, g) + fmaf(t, w1tf[nt], b1f[nt]);
            float h  = tanh_fast(hp);
            short hh = f16b(h);
            short hl = f16b(h - f16tof(hh));
            const int cb = (2 * (64 * w + 16 * nt + l15)) ^ bwXor;
            *(short*)(smem + LDS_BOUNCE + g * BSTRIDE + cb)       = hh;
            *(short*)(smem + LDS_BOUNCE + (g + 4) * BSTRIDE + cb) = hl;
        }
        __syncthreads();

        // -------- GEMM2: N-split (this wave owns d), full K=512, hi/lo in M --------
        f32x4 acc2 = (f32x4){0.f, 0.f, 0.f, 0.f};
#pragma unroll
        for (int ks = 0; ks < 16; ++ks) {
            f16x8 ha = *(const f16x8*)(smem + bounceRd + 64 * ks);
            acc2 = __builtin_amdgcn_mfma_f32_16x16x32_f16(ha, w2f[ks], acc2, 0, 0, 0);
        }
        acc2 += sx32(acc2);

        // -------- Euler update (lane-owned state), emit --------
        const float o  = pick(acc2, g) + b2v;
        const float xn = fmaf(dtv, o, xo);
        xo = xn;
        {
            short hb = f16b(xn);
            short lb = f16b(xn - f16tof(hb));
            *(short*)(smem + ys * HSLOT + g * HSTRIDE + 2 * d)       = hb;   // x_{n+1} -> slot ys
            *(short*)(smem + ys * HSLOT + (g + 4) * HSTRIDE + 2 * d) = lb;
        }
        *po = xn;
        po += B_TOT * D_DIM;

        cur = ys;
        ys  = ys + 1;
        if (ys == 11) ys = 0;
        __syncthreads();
    }
}

extern "C" void kernel_launch(void* const* d_in, const int* in_sizes, int n_in,
                              void* d_out, int out_size, void* d_ws, size_t ws_size,
                              hipStream_t stream) {
    (void)in_sizes; (void)n_in; (void)out_size; (void)d_ws; (void)ws_size;
    const float* x0  = (const float*)d_in[0];
    const float* tau = (const float*)d_in[1];
    const float* W1  = (const float*)d_in[2];
    const float* b1  = (const float*)d_in[3];
    const float* W2  = (const float*)d_in[4];
    const float* b2  = (const float*)d_in[5];
    float* out = (float*)d_out;

    ndde_kernel<<<dim3(B_TOT / ROWS), dim3(64 * WAVES), 0, stream>>>(
        x0, tau, W1, b1, W2, b2, out);
}